// Round 3
// baseline (8264.764 us; speedup 1.0000x reference)
//
#include <hip/hip_runtime.h>

typedef unsigned short u16;
typedef unsigned int u32;
typedef __attribute__((ext_vector_type(4))) float f32x4;
typedef __attribute__((ext_vector_type(8))) short s16x8;

#define B_ 64
#define T_ 512
#define E_ 1024
#define H_ 1024
#define HE_ 2048
#define N4_ 4096   // 4*H
#define NWG_ 64

__device__ __forceinline__ u16 f32_bf16(float f) {
  union { float f; u32 u; } v; v.f = f;
  u32 r = v.u + 0x7FFFu + ((v.u >> 16) & 1u);
  return (u16)(r >> 16);
}
__device__ __forceinline__ float bf16_f32(u16 h) {
  union { u32 u; float f; } v; v.u = ((u32)h) << 16;
  return v.f;
}
__device__ __forceinline__ void async16(void* lds, const void* g) {
  __builtin_amdgcn_global_load_lds(
      (const __attribute__((address_space(1))) void*)g,
      (__attribute__((address_space(3))) void*)lds, 16, 0, 0);
}
__device__ __forceinline__ float sigmoidf_(float x) {
  return 1.0f / (1.0f + __expf(-x));
}

// ---------------- fp32 -> bf16 bulk convert (4 elems/thread) ----------------
__global__ __launch_bounds__(256) void cvt4(const float* __restrict__ s,
                                            u16* __restrict__ d, int n4) {
  int i = blockIdx.x * 256 + threadIdx.x;
  if (i < n4) {
    float4 v = ((const float4*)s)[i];
    u16 o0 = f32_bf16(v.x), o1 = f32_bf16(v.y), o2 = f32_bf16(v.z), o3 = f32_bf16(v.w);
    ushort4 o; o.x = o0; o.y = o1; o.z = o2; o.w = o3;
    ((ushort4*)d)[i] = o;
  }
}

// ---------------- init: a0->bf16, bias concat, barrier reset ----------------
__global__ __launch_bounds__(256) void init_k(const float* __restrict__ a0,
                                              const float* __restrict__ bc,
                                              const float* __restrict__ bu,
                                              const float* __restrict__ bf_,
                                              const float* __restrict__ bo,
                                              u16* __restrict__ abuf0,
                                              float* __restrict__ bias4,
                                              int* __restrict__ bar) {
  int i = blockIdx.x * 256 + threadIdx.x;   // 65536 threads
  abuf0[i] = f32_bf16(a0[i]);
  if (i < N4_) {
    int g = i >> 10, h = i & 1023;
    const float* bp = (g == 0) ? bc : (g == 1) ? bu : (g == 2) ? bf_ : bo;
    bias4[i] = bp[h];
  }
  if (i < 512) bar[i] = 0;   // re-zero flags every graph replay
}

// ---------------- phase 1: P[t][b][n] = bf16( X @ WxT + bias ) ----------------
// (unchanged from verified baseline)
__global__ __launch_bounds__(256) void gemm_p1(const u16* __restrict__ Xbf,
                                               const u16* __restrict__ Wbf,
                                               const float* __restrict__ bias4,
                                               u16* __restrict__ P) {
  __shared__ __align__(16) u16 As[128 * 64];
  __shared__ __align__(16) u16 Bs[128 * 64];
  int tid = threadIdx.x;
  int wid = tid >> 6, lane = tid & 63;
  int lane15 = lane & 15, quad = lane >> 4;
  int m0 = blockIdx.y * 128, n0 = blockIdx.x * 128;
  int wm = (wid >> 1) * 64, wn = (wid & 1) * 64;

  f32x4 acc[4][4] = {};

  for (int kc = 0; kc < 1024; kc += 64) {
    __syncthreads();
    for (int i = 0; i < 8; ++i) {
      int c = wid * 8 + i;
      int o = c * 1024 + lane * 16;
      int e = (o & 16383) >> 1;
      int row = e >> 6, kcol = e & 63;
      if (o < 16384) {
        async16((char*)As + c * 1024,
                Xbf + (size_t)(m0 + row) * 1024 + kc + kcol);
      } else {
        async16((char*)Bs + (c - 16) * 1024,
                Wbf + (size_t)(n0 + row) * 2048 + 1024 + kc + kcol);
      }
    }
    __syncthreads();
    for (int s = 0; s < 2; ++s) {
      s16x8 bfrag[4], afrag[4];
      for (int ni = 0; ni < 4; ++ni)
        bfrag[ni] = *(const s16x8*)&Bs[(wn + ni * 16 + lane15) * 64 + s * 32 + quad * 8];
      for (int mi = 0; mi < 4; ++mi)
        afrag[mi] = *(const s16x8*)&As[(wm + mi * 16 + lane15) * 64 + s * 32 + quad * 8];
      for (int mi = 0; mi < 4; ++mi)
        for (int ni = 0; ni < 4; ++ni)
          acc[mi][ni] = __builtin_amdgcn_mfma_f32_16x16x32_bf16(
              afrag[mi], bfrag[ni], acc[mi][ni], 0, 0, 0);
    }
  }
  for (int mi = 0; mi < 4; ++mi) {
    int mbase = m0 + wm + mi * 16 + quad * 4;
    for (int ni = 0; ni < 4; ++ni) {
      int n = n0 + wn + ni * 16 + lane15;
      float bv = bias4[n];
      for (int r = 0; r < 4; ++r) {
        int m = mbase + r;
        int b = m >> 9, t = m & 511;
        float v = acc[mi][ni][r] + bv;
        P[(size_t)(t * 64 + b) * N4_ + n] = f32_bf16(v);
      }
    }
  }
}

// ---------------- phase 2: PERSISTENT scan kernel (k-split waves) ----------------
// 64 WGs x 256 threads, 1 WG/CU. WG hb owns h-slice [hb*16, hb*16+16).
// Wave w owns k-quarter [256w, 256w+256) of the recurrent GEMM for ALL 4 gates:
//   - A (a_prev) k-slice loaded DIRECTLY to registers (no LDS staging, no
//     K-loop barriers; 32 dwordx4/thread full-depth prefetch, compiler counts vmcnt).
//   - W slice (64 rows x 1024 k bf16 = 128KB) in LDS (swizzled), loaded once.
//   - One staggered 4-phase LDS reduction (disjoint 16-row blocks per wave per
//     phase); phase 3 fuses +P, activations, c/a update, and all global stores.
//   - Grid barrier: flag-per-WG store + wave-0 polls all 64 flags in one load.
__global__ __launch_bounds__(256, 1) void scan_k(const u16* __restrict__ Wbf,
                                                 const u16* __restrict__ P,
                                                 const float* __restrict__ c0,
                                                 u16* __restrict__ ab0,
                                                 u16* __restrict__ ab1,
                                                 float* __restrict__ a_out,
                                                 float* __restrict__ out_aT,
                                                 float* __restrict__ out_cT,
                                                 int* __restrict__ bar) {
  // LDS: [0,131072) W swizzled | [131072, +16640) f32 reduction buf [64][65]
  __shared__ __align__(16) char smem[131072 + 64 * 65 * 4];
  float* buf = (float*)(smem + 131072);

  const int tid = threadIdx.x;
  const int g = tid >> 6, lane = tid & 63;       // wave id = k-quarter
  const int lane15 = lane & 15, quad = lane >> 4;
  const int h0 = blockIdx.x * 16;
  const int kw0 = g * 256;                        // wave's k base (u16 idx)
  const int mi3 = (g + 3) & 3;                    // phase-3 owned row-block
  const int bq = mi3 * 16 + quad * 4;             // owned b rows = bq + r

  // ---- W slice -> LDS (XOR-swizzled: byte ^= (row&7)<<4), once ----
  for (int it = 0; it < 32; ++it) {
    int j = it * 256 + tid;                       // 16B chunk index, 8192 total
    int o = j * 16;
    int grow = o >> 11, kb = o & 2047;            // row (gate*16+hh), byte in row
    s16x8 v = *(const s16x8*)(Wbf +
        (size_t)((grow >> 4) * 1024 + h0 + (grow & 15)) * 2048 + (kb >> 1));
    *(s16x8*)(smem + ((grow << 11) | (kb ^ ((grow & 7) << 4)))) = v;
  }

  // ---- c0 -> regs (phase-3 ownership mapping) ----
  float c_reg[4];
#pragma unroll
  for (int r = 0; r < 4; ++r)
    c_reg[r] = c0[(bq + r) * 1024 + h0 + lane15];

  // ---- P prefetch for t=0: pc[ni*4+r] = P(t, b=bq+r, gate=ni, h=h0+lane15) ----
  u16 pc[16];
  {
    const u16* Pt = P + h0 + lane15;
#pragma unroll
    for (int r = 0; r < 4; ++r)
#pragma unroll
      for (int ni = 0; ni < 4; ++ni)
        pc[ni * 4 + r] = Pt[(size_t)(bq + r) * N4_ + ni * 1024];
  }
  __syncthreads();   // W in LDS visible

#define REDBODY(MI, PH)                                                        \
  {                                                                            \
    _Pragma("unroll") for (int ni = 0; ni < 4; ++ni)                           \
    _Pragma("unroll") for (int r = 0; r < 4; ++r) {                            \
      int ad = ((MI) * 16 + quad * 4 + r) * 65 + ni * 16 + lane15;             \
      if ((PH) == 0) buf[ad] = acc[MI][ni][r];                                 \
      else           buf[ad] += acc[MI][ni][r];                                \
    }                                                                          \
  }
#define PH3BODY(MI)                                                            \
  {                                                                            \
    _Pragma("unroll") for (int ni = 0; ni < 4; ++ni)                           \
    _Pragma("unroll") for (int r = 0; r < 4; ++r) {                            \
      float v = buf[((MI) * 16 + quad * 4 + r) * 65 + ni * 16 + lane15] +      \
                acc[MI][ni][r] + bf16_f32(pc[ni * 4 + r]);                     \
      actv[ni][r] = (ni == 0) ? tanhf(v) : sigmoidf_(v);                       \
    }                                                                          \
  }

#pragma unroll 1
  for (int t = 0; t < T_; ++t) {
    const u16* ap = (t & 1) ? ab1 : ab0;
    u16* an = (t & 1) ? ab0 : ab1;

    // ---- A k-slice -> registers (32 x dwordx4), full-depth prefetch ----
    s16x8 abuf[8][4];
#pragma unroll
    for (int c = 0; c < 8; ++c)
#pragma unroll
      for (int mi = 0; mi < 4; ++mi)
        abuf[c][mi] = *(const s16x8*)(ap + (size_t)(mi * 16 + lane15) * 1024 +
                                      kw0 + c * 32 + quad * 8);

    // ---- K-loop: zero barriers; 128 MFMA/wave ----
    f32x4 acc[4][4] = {};
#pragma unroll
    for (int c = 0; c < 8; ++c)
#pragma unroll
      for (int ni = 0; ni < 4; ++ni) {
        const int wrow = ni * 16 + lane15;
        s16x8 bfrag = *(const s16x8*)(smem + ((wrow << 11) |
            (((kw0 + c * 32 + quad * 8) * 2) ^ ((wrow & 7) << 4))));
#pragma unroll
        for (int mi = 0; mi < 4; ++mi)
          acc[mi][ni] = __builtin_amdgcn_mfma_f32_16x16x32_bf16(
              abuf[c][mi], bfrag, acc[mi][ni], 0, 0, 0);
      }

    // ---- staggered cross-wave reduction (wave-uniform ladders; static idx) ----
    {
      int m = g;                       // phase 0: init
      if (m == 0) REDBODY(0, 0) else if (m == 1) REDBODY(1, 0)
      else if (m == 2) REDBODY(2, 0) else REDBODY(3, 0)
    }
    __syncthreads();
    {
      int m = (g + 1) & 3;             // phase 1: +=
      if (m == 0) REDBODY(0, 1) else if (m == 1) REDBODY(1, 1)
      else if (m == 2) REDBODY(2, 1) else REDBODY(3, 1)
    }
    __syncthreads();
    {
      int m = (g + 2) & 3;             // phase 2: +=
      if (m == 0) REDBODY(0, 1) else if (m == 1) REDBODY(1, 1)
      else if (m == 2) REDBODY(2, 1) else REDBODY(3, 1)
    }
    __syncthreads();

    // ---- phase 3 (fused epilogue): partial + own acc + P -> act -> c/a ----
    float actv[4][4];                  // [gate][r]
    if (mi3 == 0) PH3BODY(0) else if (mi3 == 1) PH3BODY(1)
    else if (mi3 == 2) PH3BODY(2) else PH3BODY(3)

#pragma unroll
    for (int r = 0; r < 4; ++r) {
      float c1 = actv[1][r] * actv[0][r] + actv[2][r] * c_reg[r];
      c_reg[r] = c1;
      float a1 = actv[3][r] * tanhf(c1);
      int b = bq + r;
      a_out[((size_t)b * T_ + t) * H_ + h0 + lane15] = a1;
      an[b * 1024 + h0 + lane15] = f32_bf16(a1);
      if (t == T_ - 1) {
        out_aT[b * 1024 + h0 + lane15] = a1;
        out_cT[b * 1024 + h0 + lane15] = c1;
      }
    }

    // ---- grid barrier: flag-per-WG + single-load poll ----
    if (t < T_ - 1) {
      __builtin_amdgcn_fence(__ATOMIC_RELEASE, "agent");   // flush an/a_out
      __syncthreads();
      if (tid == 0)
        __hip_atomic_store(&bar[blockIdx.x], t + 1, __ATOMIC_RELAXED,
                           __HIP_MEMORY_SCOPE_AGENT);
      // P prefetch for t+1 overlaps the spin
      {
        const u16* Pt = P + (size_t)(t + 1) * 64 * N4_ + h0 + lane15;
#pragma unroll
        for (int r = 0; r < 4; ++r)
#pragma unroll
          for (int ni = 0; ni < 4; ++ni)
            pc[ni * 4 + r] = Pt[(size_t)(bq + r) * N4_ + ni * 1024];
      }
      if (tid < 64) {                  // wave 0 polls all 64 flags at once
        while (true) {
          int v = __hip_atomic_load(&bar[tid], __ATOMIC_RELAXED,
                                    __HIP_MEMORY_SCOPE_AGENT);
          if (__all(v > t)) break;
          __builtin_amdgcn_s_sleep(1);
        }
      }
      __syncthreads();
      __builtin_amdgcn_fence(__ATOMIC_ACQUIRE, "agent");   // inv L1/L2
    }
  }
#undef REDBODY
#undef PH3BODY
}

extern "C" void kernel_launch(void* const* d_in, const int* in_sizes, int n_in,
                              void* d_out, int out_size, void* d_ws, size_t ws_size,
                              hipStream_t stream) {
  const float* x_i = (const float*)d_in[0];
  const float* a0  = (const float*)d_in[1];
  const float* c0  = (const float*)d_in[2];
  const float* w[4] = {(const float*)d_in[3], (const float*)d_in[4],
                       (const float*)d_in[5], (const float*)d_in[6]};
  const float* bb[4] = {(const float*)d_in[7], (const float*)d_in[8],
                        (const float*)d_in[9], (const float*)d_in[10]};
  float* out = (float*)d_out;

  char* ws = (char*)d_ws;
  u16* Wbf   = (u16*)ws;                          // 16,777,216 B
  u16* Xbf   = (u16*)(ws + 16777216);             // 67,108,864 B
  u16* P     = (u16*)(ws + 83886080);             // 268,435,456 B
  float* bias4 = (float*)(ws + 352321536);        // 16,384 B
  u16* abuf0 = (u16*)(ws + 352337920);             // 131,072 B
  u16* abuf1 = (u16*)(ws + 352468992);             // 131,072 B
  int* bar   = (int*)(ws + 352600064);             // 2,048 B

  for (int g = 0; g < 4; ++g)
    cvt4<<<2048, 256, 0, stream>>>(w[g], Wbf + (size_t)g * 1024 * 2048, 524288);
  cvt4<<<32768, 256, 0, stream>>>(x_i, Xbf, 8388608);
  init_k<<<256, 256, 0, stream>>>(a0, bb[0], bb[1], bb[2], bb[3],
                                  abuf0, bias4, bar);
  gemm_p1<<<dim3(32, 256), 256, 0, stream>>>(Xbf, Wbf, bias4, P);
  // phase 2: single persistent kernel, k-split waves, flag barrier
  scan_k<<<64, 256, 0, stream>>>(Wbf, P, c0, abuf0, abuf1,
                                 out, out + 33554432, out + 33619968, bar);
}

// Round 4
// 5253.602 us; speedup vs baseline: 1.5732x; 1.5732x over previous
//
#include <hip/hip_runtime.h>

typedef unsigned short u16;
typedef unsigned int u32;
typedef __attribute__((ext_vector_type(4))) float f32x4;
typedef __attribute__((ext_vector_type(8))) short s16x8;

#define B_ 64
#define T_ 512
#define E_ 1024
#define H_ 1024
#define HE_ 2048
#define N4_ 4096   // 4*H
#define NWG_ 64

__device__ __forceinline__ u16 f32_bf16(float f) {
  union { float f; u32 u; } v; v.f = f;
  u32 r = v.u + 0x7FFFu + ((v.u >> 16) & 1u);
  return (u16)(r >> 16);
}
__device__ __forceinline__ float bf16_f32(u16 h) {
  union { u32 u; float f; } v; v.u = ((u32)h) << 16;
  return v.f;
}
__device__ __forceinline__ void async16(void* lds, const void* g) {
  __builtin_amdgcn_global_load_lds(
      (const __attribute__((address_space(1))) void*)g,
      (__attribute__((address_space(3))) void*)lds, 16, 0, 0);
}
__device__ __forceinline__ float sigmoidf_(float x) {
  return 1.0f / (1.0f + __expf(-x));
}
// coherent (LLC-direct, bypass L1+L2) 16B load / 2B store for the a-buffers
__device__ __forceinline__ s16x8 load16_cc(const u16* p) {
  s16x8 r;
  asm volatile("global_load_dwordx4 %0, %1, off sc0 sc1"
               : "=v"(r) : "v"(p) : "memory");
  return r;
}
__device__ __forceinline__ void store2_cc(u16* p, u16 v) {
  asm volatile("global_store_short %0, %1, off sc0 sc1"
               :: "v"(p), "v"((u32)v) : "memory");
}

// ---------------- fp32 -> bf16 bulk convert (4 elems/thread) ----------------
__global__ __launch_bounds__(256) void cvt4(const float* __restrict__ s,
                                            u16* __restrict__ d, int n4) {
  int i = blockIdx.x * 256 + threadIdx.x;
  if (i < n4) {
    float4 v = ((const float4*)s)[i];
    u16 o0 = f32_bf16(v.x), o1 = f32_bf16(v.y), o2 = f32_bf16(v.z), o3 = f32_bf16(v.w);
    ushort4 o; o.x = o0; o.y = o1; o.z = o2; o.w = o3;
    ((ushort4*)d)[i] = o;
  }
}

// ---------------- init: a0->bf16, bias concat, barrier reset ----------------
__global__ __launch_bounds__(256) void init_k(const float* __restrict__ a0,
                                              const float* __restrict__ bc,
                                              const float* __restrict__ bu,
                                              const float* __restrict__ bf_,
                                              const float* __restrict__ bo,
                                              u16* __restrict__ abuf0,
                                              float* __restrict__ bias4,
                                              int* __restrict__ bar) {
  int i = blockIdx.x * 256 + threadIdx.x;   // 65536 threads
  abuf0[i] = f32_bf16(a0[i]);
  if (i < N4_) {
    int g = i >> 10, h = i & 1023;
    const float* bp = (g == 0) ? bc : (g == 1) ? bu : (g == 2) ? bf_ : bo;
    bias4[i] = bp[h];
  }
  if (i < 512) bar[i] = 0;   // re-zero flags every graph replay
}

// ---------------- phase 1: P[t][b][n] = bf16( X @ WxT + bias ) ----------------
// (unchanged from verified baseline)
__global__ __launch_bounds__(256) void gemm_p1(const u16* __restrict__ Xbf,
                                               const u16* __restrict__ Wbf,
                                               const float* __restrict__ bias4,
                                               u16* __restrict__ P) {
  __shared__ __align__(16) u16 As[128 * 64];
  __shared__ __align__(16) u16 Bs[128 * 64];
  int tid = threadIdx.x;
  int wid = tid >> 6, lane = tid & 63;
  int lane15 = lane & 15, quad = lane >> 4;
  int m0 = blockIdx.y * 128, n0 = blockIdx.x * 128;
  int wm = (wid >> 1) * 64, wn = (wid & 1) * 64;

  f32x4 acc[4][4] = {};

  for (int kc = 0; kc < 1024; kc += 64) {
    __syncthreads();
    for (int i = 0; i < 8; ++i) {
      int c = wid * 8 + i;
      int o = c * 1024 + lane * 16;
      int e = (o & 16383) >> 1;
      int row = e >> 6, kcol = e & 63;
      if (o < 16384) {
        async16((char*)As + c * 1024,
                Xbf + (size_t)(m0 + row) * 1024 + kc + kcol);
      } else {
        async16((char*)Bs + (c - 16) * 1024,
                Wbf + (size_t)(n0 + row) * 2048 + 1024 + kc + kcol);
      }
    }
    __syncthreads();
    for (int s = 0; s < 2; ++s) {
      s16x8 bfrag[4], afrag[4];
      for (int ni = 0; ni < 4; ++ni)
        bfrag[ni] = *(const s16x8*)&Bs[(wn + ni * 16 + lane15) * 64 + s * 32 + quad * 8];
      for (int mi = 0; mi < 4; ++mi)
        afrag[mi] = *(const s16x8*)&As[(wm + mi * 16 + lane15) * 64 + s * 32 + quad * 8];
      for (int mi = 0; mi < 4; ++mi)
        for (int ni = 0; ni < 4; ++ni)
          acc[mi][ni] = __builtin_amdgcn_mfma_f32_16x16x32_bf16(
              afrag[mi], bfrag[ni], acc[mi][ni], 0, 0, 0);
    }
  }
  for (int mi = 0; mi < 4; ++mi) {
    int mbase = m0 + wm + mi * 16 + quad * 4;
    for (int ni = 0; ni < 4; ++ni) {
      int n = n0 + wn + ni * 16 + lane15;
      float bv = bias4[n];
      for (int r = 0; r < 4; ++r) {
        int m = mbase + r;
        int b = m >> 9, t = m & 511;
        float v = acc[mi][ni][r] + bv;
        P[(size_t)(t * 64 + b) * N4_ + n] = f32_bf16(v);
      }
    }
  }
}

// ---------------- phase 2: PERSISTENT scan kernel (fence-free barrier) ----------
// 64 WGs x 256 threads, 1 WG/CU. WG hb owns h-slice [hb*16, hb*16+16).
// Wave w owns k-quarter [256w, 256w+256) of the recurrent GEMM for ALL 4 gates.
// NO agent fences (no buffer_wbl2 / buffer_inv per step). The only in-kernel
// cross-WG data (a-buffers, flags) uses sc0 sc1 LLC-direct accesses:
//   - a_prev k-slice: raw global_load_dwordx4 sc0 sc1 -> regs; one vmcnt(0) +
//     sched_barrier(0) before the K-loop (counted vmcnt unsafe: compiler vmem
//     interleaves).
//   - a_next: global_store_short sc0 sc1; release = vmcnt(0) + __syncthreads
//     before the relaxed flag store (nothing dirty in L2 -> no wb needed).
//   - acquire = data-dep on the flag poll (sc1 loads can't hit stale L2).
//   P/W/c are read-only in-kernel -> plain cached loads now SURVIVE in L2
//   across steps (no per-step invalidate).
__global__ __launch_bounds__(256, 1) void scan_k(const u16* __restrict__ Wbf,
                                                 const u16* __restrict__ P,
                                                 const float* __restrict__ c0,
                                                 u16* __restrict__ ab0,
                                                 u16* __restrict__ ab1,
                                                 float* __restrict__ a_out,
                                                 float* __restrict__ out_aT,
                                                 float* __restrict__ out_cT,
                                                 int* __restrict__ bar) {
  // LDS: [0,131072) W swizzled | [131072, +16640) f32 reduction buf [64][65]
  __shared__ __align__(16) char smem[131072 + 64 * 65 * 4];
  float* buf = (float*)(smem + 131072);

  const int tid = threadIdx.x;
  const int g = tid >> 6, lane = tid & 63;       // wave id = k-quarter
  const int lane15 = lane & 15, quad = lane >> 4;
  const int h0 = blockIdx.x * 16;
  const int kw0 = g * 256;                        // wave's k base (u16 idx)
  const int mi3 = (g + 3) & 3;                    // phase-3 owned row-block
  const int bq = mi3 * 16 + quad * 4;             // owned b rows = bq + r

  // ---- W slice -> LDS (XOR-swizzled: byte ^= (row&7)<<4), once ----
  for (int it = 0; it < 32; ++it) {
    int j = it * 256 + tid;                       // 16B chunk index, 8192 total
    int o = j * 16;
    int grow = o >> 11, kb = o & 2047;            // row (gate*16+hh), byte in row
    s16x8 v = *(const s16x8*)(Wbf +
        (size_t)((grow >> 4) * 1024 + h0 + (grow & 15)) * 2048 + (kb >> 1));
    *(s16x8*)(smem + ((grow << 11) | (kb ^ ((grow & 7) << 4)))) = v;
  }

  // ---- c0 -> regs (phase-3 ownership mapping) ----
  float c_reg[4];
#pragma unroll
  for (int r = 0; r < 4; ++r)
    c_reg[r] = c0[(bq + r) * 1024 + h0 + lane15];

  // ---- P prefetch for t=0: pc[ni*4+r] = P(t, b=bq+r, gate=ni, h=h0+lane15) ----
  u16 pc[16];
  {
    const u16* Pt = P + h0 + lane15;
#pragma unroll
    for (int r = 0; r < 4; ++r)
#pragma unroll
      for (int ni = 0; ni < 4; ++ni)
        pc[ni * 4 + r] = Pt[(size_t)(bq + r) * N4_ + ni * 1024];
  }
  __syncthreads();   // W in LDS visible

#define REDBODY(MI, PH)                                                        \
  {                                                                            \
    _Pragma("unroll") for (int ni = 0; ni < 4; ++ni)                           \
    _Pragma("unroll") for (int r = 0; r < 4; ++r) {                            \
      int ad = ((MI) * 16 + quad * 4 + r) * 65 + ni * 16 + lane15;             \
      if ((PH) == 0) buf[ad] = acc[MI][ni][r];                                 \
      else           buf[ad] += acc[MI][ni][r];                                \
    }                                                                          \
  }
#define PH3BODY(MI)                                                            \
  {                                                                            \
    _Pragma("unroll") for (int ni = 0; ni < 4; ++ni)                           \
    _Pragma("unroll") for (int r = 0; r < 4; ++r) {                            \
      float v = buf[((MI) * 16 + quad * 4 + r) * 65 + ni * 16 + lane15] +      \
                acc[MI][ni][r] + bf16_f32(pc[ni * 4 + r]);                     \
      actv[ni][r] = (ni == 0) ? tanhf(v) : sigmoidf_(v);                       \
    }                                                                          \
  }

#pragma unroll 1
  for (int t = 0; t < T_; ++t) {
    const u16* ap = (t & 1) ? ab1 : ab0;
    u16* an = (t & 1) ? ab0 : ab1;

    // ---- A k-slice -> regs: 32 x dwordx4 sc0 sc1 (LLC-direct), then one wait ----
    s16x8 abuf[8][4];
#pragma unroll
    for (int c = 0; c < 8; ++c)
#pragma unroll
      for (int mi = 0; mi < 4; ++mi)
        abuf[c][mi] = load16_cc(ap + (size_t)(mi * 16 + lane15) * 1024 +
                                kw0 + c * 32 + quad * 8);
    asm volatile("s_waitcnt vmcnt(0)" ::: "memory");
    __builtin_amdgcn_sched_barrier(0);   // rule #18: pin MFMAs below the wait

    // ---- K-loop: zero barriers; 128 MFMA/wave ----
    f32x4 acc[4][4] = {};
#pragma unroll
    for (int c = 0; c < 8; ++c)
#pragma unroll
      for (int ni = 0; ni < 4; ++ni) {
        const int wrow = ni * 16 + lane15;
        s16x8 bfrag = *(const s16x8*)(smem + ((wrow << 11) |
            (((kw0 + c * 32 + quad * 8) * 2) ^ ((wrow & 7) << 4))));
#pragma unroll
        for (int mi = 0; mi < 4; ++mi)
          acc[mi][ni] = __builtin_amdgcn_mfma_f32_16x16x32_bf16(
              abuf[c][mi], bfrag, acc[mi][ni], 0, 0, 0);
      }

    // ---- staggered cross-wave reduction (wave-uniform ladders; static idx) ----
    {
      int m = g;                       // phase 0: init
      if (m == 0) REDBODY(0, 0) else if (m == 1) REDBODY(1, 0)
      else if (m == 2) REDBODY(2, 0) else REDBODY(3, 0)
    }
    __syncthreads();
    {
      int m = (g + 1) & 3;             // phase 1: +=
      if (m == 0) REDBODY(0, 1) else if (m == 1) REDBODY(1, 1)
      else if (m == 2) REDBODY(2, 1) else REDBODY(3, 1)
    }
    __syncthreads();
    {
      int m = (g + 2) & 3;             // phase 2: +=
      if (m == 0) REDBODY(0, 1) else if (m == 1) REDBODY(1, 1)
      else if (m == 2) REDBODY(2, 1) else REDBODY(3, 1)
    }
    __syncthreads();

    // ---- phase 3 (fused epilogue): partial + own acc + P -> act -> c/a ----
    float actv[4][4];                  // [gate][r]
    if (mi3 == 0) PH3BODY(0) else if (mi3 == 1) PH3BODY(1)
    else if (mi3 == 2) PH3BODY(2) else PH3BODY(3)

    float a1v[4], c1v[4];
#pragma unroll
    for (int r = 0; r < 4; ++r) {
      float c1 = actv[1][r] * actv[0][r] + actv[2][r] * c_reg[r];
      c_reg[r] = c1; c1v[r] = c1;
      a1v[r] = actv[3][r] * tanhf(c1);
    }

    if (t < T_ - 1) {
      // ---- release: a_next (sc0 sc1, LLC-direct) -> wait -> sync -> flag ----
#pragma unroll
      for (int r = 0; r < 4; ++r)
        store2_cc(an + (bq + r) * 1024 + h0 + lane15, f32_bf16(a1v[r]));
      asm volatile("s_waitcnt vmcnt(0)" ::: "memory");
      __syncthreads();                 // all waves' an-stores complete
      if (tid == 0)
        __hip_atomic_store(&bar[blockIdx.x], t + 1, __ATOMIC_RELAXED,
                           __HIP_MEMORY_SCOPE_AGENT);
    }

    // ---- outputs (plain cached stores; overlap the spin) ----
#pragma unroll
    for (int r = 0; r < 4; ++r)
      a_out[((size_t)(bq + r) * T_ + t) * H_ + h0 + lane15] = a1v[r];
    if (t == T_ - 1) {
#pragma unroll
      for (int r = 0; r < 4; ++r) {
        out_aT[(bq + r) * 1024 + h0 + lane15] = a1v[r];
        out_cT[(bq + r) * 1024 + h0 + lane15] = c1v[r];
      }
    }

    if (t < T_ - 1) {
      // ---- P prefetch for t+1 overlaps the spin (plain cached loads) ----
      {
        const u16* Pt = P + (size_t)(t + 1) * 64 * N4_ + h0 + lane15;
#pragma unroll
        for (int r = 0; r < 4; ++r)
#pragma unroll
          for (int ni = 0; ni < 4; ++ni)
            pc[ni * 4 + r] = Pt[(size_t)(bq + r) * N4_ + ni * 1024];
      }
      // ---- every wave polls all 64 flags; no post-poll sync needed ----
      while (true) {
        int v = __hip_atomic_load(&bar[lane], __ATOMIC_RELAXED,
                                  __HIP_MEMORY_SCOPE_AGENT);
        if (__all(v > t)) break;
        __builtin_amdgcn_s_sleep(1);
      }
    }
  }
#undef REDBODY
#undef PH3BODY
}

extern "C" void kernel_launch(void* const* d_in, const int* in_sizes, int n_in,
                              void* d_out, int out_size, void* d_ws, size_t ws_size,
                              hipStream_t stream) {
  const float* x_i = (const float*)d_in[0];
  const float* a0  = (const float*)d_in[1];
  const float* c0  = (const float*)d_in[2];
  const float* w[4] = {(const float*)d_in[3], (const float*)d_in[4],
                       (const float*)d_in[5], (const float*)d_in[6]};
  const float* bb[4] = {(const float*)d_in[7], (const float*)d_in[8],
                        (const float*)d_in[9], (const float*)d_in[10]};
  float* out = (float*)d_out;

  char* ws = (char*)d_ws;
  u16* Wbf   = (u16*)ws;                          // 16,777,216 B
  u16* Xbf   = (u16*)(ws + 16777216);             // 67,108,864 B
  u16* P     = (u16*)(ws + 83886080);             // 268,435,456 B
  float* bias4 = (float*)(ws + 352321536);        // 16,384 B
  u16* abuf0 = (u16*)(ws + 352337920);            // 131,072 B
  u16* abuf1 = (u16*)(ws + 352468992);            // 131,072 B
  int* bar   = (int*)(ws + 352600064);            // 2,048 B

  for (int g = 0; g < 4; ++g)
    cvt4<<<2048, 256, 0, stream>>>(w[g], Wbf + (size_t)g * 1024 * 2048, 524288);
  cvt4<<<32768, 256, 0, stream>>>(x_i, Xbf, 8388608);
  init_k<<<256, 256, 0, stream>>>(a0, bb[0], bb[1], bb[2], bb[3],
                                  abuf0, bias4, bar);
  gemm_p1<<<dim3(32, 256), 256, 0, stream>>>(Xbf, Wbf, bias4, P);
  // phase 2: single persistent kernel, fence-free step barrier
  scan_k<<<64, 256, 0, stream>>>(Wbf, P, c0, abuf0, abuf1,
                                 out, out + 33554432, out + 33619968, bar);
}

// Round 5
// 3360.507 us; speedup vs baseline: 2.4594x; 1.5633x over previous
//
#include <hip/hip_runtime.h>

typedef unsigned short u16;
typedef unsigned int u32;
typedef __attribute__((ext_vector_type(4))) float f32x4;
typedef __attribute__((ext_vector_type(8))) short s16x8;

#define B_ 64
#define T_ 512
#define E_ 1024
#define H_ 1024
#define HE_ 2048
#define N4_ 4096   // 4*H

__device__ __forceinline__ u16 f32_bf16(float f) {
  union { float f; u32 u; } v; v.f = f;
  u32 r = v.u + 0x7FFFu + ((v.u >> 16) & 1u);
  return (u16)(r >> 16);
}
__device__ __forceinline__ float bf16_f32(u16 h) {
  union { u32 u; float f; } v; v.u = ((u32)h) << 16;
  return v.f;
}
__device__ __forceinline__ void async16(void* lds, const void* g) {
  __builtin_amdgcn_global_load_lds(
      (const __attribute__((address_space(1))) void*)g,
      (__attribute__((address_space(3))) void*)lds, 16, 0, 0);
}
__device__ __forceinline__ float sigmoidf_(float x) {
  return 1.0f / (1.0f + __expf(-x));
}
// coherent (LLC-direct, bypass L1+L2) accesses for cross-WG a-buffers
__device__ __forceinline__ s16x8 load16_cc(const u16* p) {
  s16x8 r;
  asm volatile("global_load_dwordx4 %0, %1, off sc0 sc1"
               : "=v"(r) : "v"(p) : "memory");
  return r;
}
__device__ __forceinline__ void store2_cc(u16* p, u16 v) {
  asm volatile("global_store_short %0, %1, off sc0 sc1"
               :: "v"(p), "v"((u32)v) : "memory");
}

// ---------------- fp32 -> bf16 bulk convert (4 elems/thread) ----------------
__global__ __launch_bounds__(256) void cvt4(const float* __restrict__ s,
                                            u16* __restrict__ d, int n4) {
  int i = blockIdx.x * 256 + threadIdx.x;
  if (i < n4) {
    float4 v = ((const float4*)s)[i];
    u16 o0 = f32_bf16(v.x), o1 = f32_bf16(v.y), o2 = f32_bf16(v.z), o3 = f32_bf16(v.w);
    ushort4 o; o.x = o0; o.y = o1; o.z = o2; o.w = o3;
    ((ushort4*)d)[i] = o;
  }
}

// ---------------- init: a0->bf16, bias concat, barrier reset ----------------
__global__ __launch_bounds__(256) void init_k(const float* __restrict__ a0,
                                              const float* __restrict__ bc,
                                              const float* __restrict__ bu,
                                              const float* __restrict__ bf_,
                                              const float* __restrict__ bo,
                                              u16* __restrict__ abuf0,
                                              float* __restrict__ bias4,
                                              int* __restrict__ bar) {
  int i = blockIdx.x * 256 + threadIdx.x;   // 65536 threads
  abuf0[i] = f32_bf16(a0[i]);
  if (i < N4_) {
    int g = i >> 10, h = i & 1023;
    const float* bp = (g == 0) ? bc : (g == 1) ? bu : (g == 2) ? bf_ : bo;
    bias4[i] = bp[h];
  }
  if (i < 512) bar[i] = 0;   // re-zero flags every graph replay
}

// ---------------- phase 1: P[t][b][n] = bf16( X @ WxT + bias ) ----------------
// (unchanged from verified baseline)
__global__ __launch_bounds__(256) void gemm_p1(const u16* __restrict__ Xbf,
                                               const u16* __restrict__ Wbf,
                                               const float* __restrict__ bias4,
                                               u16* __restrict__ P) {
  __shared__ __align__(16) u16 As[128 * 64];
  __shared__ __align__(16) u16 Bs[128 * 64];
  int tid = threadIdx.x;
  int wid = tid >> 6, lane = tid & 63;
  int lane15 = lane & 15, quad = lane >> 4;
  int m0 = blockIdx.y * 128, n0 = blockIdx.x * 128;
  int wm = (wid >> 1) * 64, wn = (wid & 1) * 64;

  f32x4 acc[4][4] = {};

  for (int kc = 0; kc < 1024; kc += 64) {
    __syncthreads();
    for (int i = 0; i < 8; ++i) {
      int c = wid * 8 + i;
      int o = c * 1024 + lane * 16;
      int e = (o & 16383) >> 1;
      int row = e >> 6, kcol = e & 63;
      if (o < 16384) {
        async16((char*)As + c * 1024,
                Xbf + (size_t)(m0 + row) * 1024 + kc + kcol);
      } else {
        async16((char*)Bs + (c - 16) * 1024,
                Wbf + (size_t)(n0 + row) * 2048 + 1024 + kc + kcol);
      }
    }
    __syncthreads();
    for (int s = 0; s < 2; ++s) {
      s16x8 bfrag[4], afrag[4];
      for (int ni = 0; ni < 4; ++ni)
        bfrag[ni] = *(const s16x8*)&Bs[(wn + ni * 16 + lane15) * 64 + s * 32 + quad * 8];
      for (int mi = 0; mi < 4; ++mi)
        afrag[mi] = *(const s16x8*)&As[(wm + mi * 16 + lane15) * 64 + s * 32 + quad * 8];
      for (int mi = 0; mi < 4; ++mi)
        for (int ni = 0; ni < 4; ++ni)
          acc[mi][ni] = __builtin_amdgcn_mfma_f32_16x16x32_bf16(
              afrag[mi], bfrag[ni], acc[mi][ni], 0, 0, 0);
    }
  }
  for (int mi = 0; mi < 4; ++mi) {
    int mbase = m0 + wm + mi * 16 + quad * 4;
    for (int ni = 0; ni < 4; ++ni) {
      int n = n0 + wn + ni * 16 + lane15;
      float bv = bias4[n];
      for (int r = 0; r < 4; ++r) {
        int m = mbase + r;
        int b = m >> 9, t = m & 511;
        float v = acc[mi][ni][r] + bv;
        P[(size_t)(t * 64 + b) * N4_ + n] = f32_bf16(v);
      }
    }
  }
}

// ---------------- phase 2: PERSISTENT scan, 4 independent batch groups --------
// Grid 256 WGs = 1/CU (whole chip). Group grp = blockIdx>>6 owns batch rows
// [grp*16, grp*16+16) — batch rows are INDEPENDENT recurrences, so groups never
// synchronize with each other. Within a group, 64 WGs h-split (16 wide); wave w
// owns k-quarter [256w,256w+256).
//   - exchange per step per group: 32 KB (was 128 KB over all 64 b).
//   - a-load: 8 x dwordx4 sc0 sc1 -> regs (was 32).
//   - reduction: ONE __syncthreads; all 4 wave-partials -> LDS [4][16][66]
//     (stride 66 -> 2-way bank aliasing = free); epilogue thread owns one
//     (b,h): sums 16 partials, computes all 4 gates locally (act-LDS pass and
//     2 barriers eliminated).
//   - fence-free coherence as R4: sc0 sc1 for a-buffers, relaxed flags,
//     release = vmcnt(0)+syncthreads, acquire = data-dep on poll.
__global__ __launch_bounds__(256, 1) void scan_k(const u16* __restrict__ Wbf,
                                                 const u16* __restrict__ P,
                                                 const float* __restrict__ c0,
                                                 u16* __restrict__ ab0,
                                                 u16* __restrict__ ab1,
                                                 float* __restrict__ a_out,
                                                 float* __restrict__ out_aT,
                                                 float* __restrict__ out_cT,
                                                 int* __restrict__ bar) {
  // LDS: [0,131072) W swizzled | [131072, +16896) f32 buf [4][16][66]
  __shared__ __align__(16) char smem[131072 + 4 * 16 * 66 * 4];
  float* buf = (float*)(smem + 131072);

  const int tid = threadIdx.x;
  const int g = tid >> 6, lane = tid & 63;       // wave id = k-quarter
  const int lane15 = lane & 15, quad = lane >> 4;
  const int grp = blockIdx.x >> 6;                // batch group (0..3)
  const int hb  = blockIdx.x & 63;                // h-slice index (0..63)
  const int h0 = hb * 16;
  const int b0 = grp * 16;                        // group batch base
  const int kw0 = g * 256;                        // wave's k base (u16 idx)
  int* gbar = bar + grp * 64;                     // group's 64 flags

  // epilogue ownership: thread -> (b = b0 + (tid>>4), h = h0 + (tid&15))
  const int eb = tid >> 4, ehh = tid & 15;
  const int bg = b0 + eb;

  // ---- W slice -> LDS (XOR-swizzled: byte ^= (row&7)<<4), once ----
  for (int it = 0; it < 32; ++it) {
    int j = it * 256 + tid;                       // 16B chunk index, 8192 total
    int o = j * 16;
    int grow = o >> 11, kb = o & 2047;            // row (gate*16+hh), byte in row
    s16x8 v = *(const s16x8*)(Wbf +
        (size_t)((grow >> 4) * 1024 + h0 + (grow & 15)) * 2048 + (kb >> 1));
    *(s16x8*)(smem + ((grow << 11) | (kb ^ ((grow & 7) << 4)))) = v;
  }

  // ---- c0 -> reg (one (b,h) per thread) ----
  float c_reg = c0[bg * 1024 + h0 + ehh];

  // ---- P prefetch for t=0: pc[gate] ----
  u16 pc[4];
#pragma unroll
  for (int ni = 0; ni < 4; ++ni)
    pc[ni] = P[(size_t)bg * N4_ + ni * 1024 + h0 + ehh];
  __syncthreads();   // W in LDS visible

#pragma unroll 1
  for (int t = 0; t < T_; ++t) {
    const u16* ap = (t & 1) ? ab1 : ab0;
    u16* an = (t & 1) ? ab0 : ab1;

    // ---- A k-slice -> regs: 8 x dwordx4 sc0 sc1 (group's 16 rows) ----
    s16x8 abuf[8];
#pragma unroll
    for (int c = 0; c < 8; ++c)
      abuf[c] = load16_cc(ap + (size_t)(b0 + lane15) * 1024 +
                          kw0 + c * 32 + quad * 8);
    asm volatile("s_waitcnt vmcnt(0)" ::: "memory");
    __builtin_amdgcn_sched_barrier(0);   // rule #18: keep MFMAs below the wait

    // ---- 32 MFMA/wave (M=16 rows, N=4 gate-tiles, K=256) ----
    f32x4 acc[4] = {};
#pragma unroll
    for (int c = 0; c < 8; ++c)
#pragma unroll
      for (int ni = 0; ni < 4; ++ni) {
        const int wrow = ni * 16 + lane15;
        s16x8 bfrag = *(const s16x8*)(smem + ((wrow << 11) |
            (((kw0 + c * 32 + quad * 8) * 2) ^ ((wrow & 7) << 4))));
        acc[ni] = __builtin_amdgcn_mfma_f32_16x16x32_bf16(
            abuf[c], bfrag, acc[ni], 0, 0, 0);
      }

    // ---- all 4 wave-partials -> LDS, one sync ----
    // acc[ni][r] is C(b = quad*4+r, n = ni*16+lane15) partial for k-quarter g
#pragma unroll
    for (int ni = 0; ni < 4; ++ni)
#pragma unroll
      for (int r = 0; r < 4; ++r)
        buf[(g * 16 + quad * 4 + r) * 66 + ni * 16 + lane15] = acc[ni][r];
    __syncthreads();

    // ---- fused epilogue: sum 4 partials/gate + P -> gates -> c,a ----
    float s0 = 0.f, s1 = 0.f, s2 = 0.f, s3 = 0.f;
#pragma unroll
    for (int w = 0; w < 4; ++w) {
      int base = (w * 16 + eb) * 66 + ehh;
      s0 += buf[base];
      s1 += buf[base + 16];
      s2 += buf[base + 32];
      s3 += buf[base + 48];
    }
    float cand = tanhf(s0 + bf16_f32(pc[0]));
    float uu   = sigmoidf_(s1 + bf16_f32(pc[1]));
    float ff   = sigmoidf_(s2 + bf16_f32(pc[2]));
    float oo   = sigmoidf_(s3 + bf16_f32(pc[3]));
    float c1 = uu * cand + ff * c_reg;
    c_reg = c1;
    float a1 = oo * tanhf(c1);
    a_out[((size_t)bg * T_ + t) * H_ + h0 + ehh] = a1;

    if (t < T_ - 1) {
      // ---- release: a_next (sc0 sc1) -> wait -> sync -> flag ----
      store2_cc(an + bg * 1024 + h0 + ehh, f32_bf16(a1));
      asm volatile("s_waitcnt vmcnt(0)" ::: "memory");
      __syncthreads();                 // all waves' an-stores acked
      if (tid == 0)
        __hip_atomic_store(&gbar[hb], t + 1, __ATOMIC_RELAXED,
                           __HIP_MEMORY_SCOPE_AGENT);
      // ---- P prefetch for t+1 overlaps the spin ----
      {
        const u16* Pt = P + (size_t)(t + 1) * 64 * N4_ + (size_t)bg * N4_ +
                        h0 + ehh;
#pragma unroll
        for (int ni = 0; ni < 4; ++ni)
          pc[ni] = Pt[ni * 1024];
      }
      // ---- every wave polls the group's 64 flags ----
      while (true) {
        int v = __hip_atomic_load(&gbar[lane], __ATOMIC_RELAXED,
                                  __HIP_MEMORY_SCOPE_AGENT);
        if (__all(v > t)) break;
        __builtin_amdgcn_s_sleep(1);
      }
    } else {
      out_aT[bg * 1024 + h0 + ehh] = a1;
      out_cT[bg * 1024 + h0 + ehh] = c1;
    }
  }
}

extern "C" void kernel_launch(void* const* d_in, const int* in_sizes, int n_in,
                              void* d_out, int out_size, void* d_ws, size_t ws_size,
                              hipStream_t stream) {
  const float* x_i = (const float*)d_in[0];
  const float* a0  = (const float*)d_in[1];
  const float* c0  = (const float*)d_in[2];
  const float* w[4] = {(const float*)d_in[3], (const float*)d_in[4],
                       (const float*)d_in[5], (const float*)d_in[6]};
  const float* bb[4] = {(const float*)d_in[7], (const float*)d_in[8],
                        (const float*)d_in[9], (const float*)d_in[10]};
  float* out = (float*)d_out;

  char* ws = (char*)d_ws;
  u16* Wbf   = (u16*)ws;                          // 16,777,216 B
  u16* Xbf   = (u16*)(ws + 16777216);             // 67,108,864 B
  u16* P     = (u16*)(ws + 83886080);             // 268,435,456 B
  float* bias4 = (float*)(ws + 352321536);        // 16,384 B
  u16* abuf0 = (u16*)(ws + 352337920);            // 131,072 B
  u16* abuf1 = (u16*)(ws + 352468992);            // 131,072 B
  int* bar   = (int*)(ws + 352600064);            // 2,048 B

  for (int g = 0; g < 4; ++g)
    cvt4<<<2048, 256, 0, stream>>>(w[g], Wbf + (size_t)g * 1024 * 2048, 524288);
  cvt4<<<32768, 256, 0, stream>>>(x_i, Xbf, 8388608);
  init_k<<<256, 256, 0, stream>>>(a0, bb[0], bb[1], bb[2], bb[3],
                                  abuf0, bias4, bar);
  gemm_p1<<<dim3(32, 256), 256, 0, stream>>>(Xbf, Wbf, bias4, P);
  // phase 2: 4 independent batch groups x 64 h-split WGs, 1 WG/CU, whole chip
  scan_k<<<256, 256, 0, stream>>>(Wbf, P, c0, abuf0, abuf1,
                                  out, out + 33554432, out + 33619968, bar);
}